// Round 1
// baseline (6002.277 us; speedup 1.0000x reference)
//
#include <hip/hip_runtime.h>
#include <stdint.h>
#include <stddef.h>

// Reverse LSTM: T=256, B=64, D=H=1024.
// Phase 0: cast x, W_ih, h0 to bf16 (ws).
// Phase 1: P[t][n][b] = bf16( x[t,b,:]@W_ih[n,:] + b_ih[n] + b_hh[n] )   (bf16 MFMA GEMM)
// Phase 2: persistent cooperative kernel, 64 WGs (one per hidden-unit block of 16),
//          per-step: gates = P + h@W_hh_sliceT (W_hh slice resident in LDS, bf16,
//          XOR-swizzled), pointwise in f32, c in registers, h double-buffered in ws,
//          device-wide flag barrier per step.

typedef unsigned short u16;
typedef __attribute__((ext_vector_type(4))) unsigned short u16x4;
typedef __attribute__((ext_vector_type(8))) short short8;
typedef __attribute__((ext_vector_type(4))) float f32x4;

#define T_LEN 256
#define YS_ELEMS (256 * 64 * 1024)  // 16777216

__device__ __forceinline__ u16 f2bf(float f) {
  union { float f; unsigned int i; } v; v.f = f;
  unsigned int r = v.i + 0x7FFFu + ((v.i >> 16) & 1u);  // RNE
  return (u16)(r >> 16);
}
__device__ __forceinline__ float bf2f(u16 u) {
  union { unsigned int i; float f; } v; v.i = ((unsigned int)u) << 16; return v.f;
}
__device__ __forceinline__ void gload_lds16(const void* g, void* l) {
  __builtin_amdgcn_global_load_lds(
      (const __attribute__((address_space(1))) unsigned int*)g,
      (__attribute__((address_space(3))) unsigned int*)l, 16, 0, 0);
}

// ---------------- Phase 0: f32 -> bf16 cast ----------------
__global__ void cast_f32_bf16(const float* __restrict__ src, u16* __restrict__ dst, int n4) {
  int i = blockIdx.x * blockDim.x + threadIdx.x;
  const int stride = gridDim.x * blockDim.x;
  for (; i < n4; i += stride) {
    float4 v = ((const float4*)src)[i];
    u16x4 o;
    o[0] = f2bf(v.x); o[1] = f2bf(v.y); o[2] = f2bf(v.z); o[3] = f2bf(v.w);
    ((u16x4*)dst)[i] = o;
  }
}

// ---------------- Phase 1: pregate GEMM ----------------
// C[M=16384][N=4096] = X[M][1024] * Wih[N][1024]^T + bias, stored as P[t][n][b] bf16.
// 128x128 tile, BK=64, 4 waves (2x2), global_load_lds w16 with pre-swizzled source,
// XOR-swizzled LDS reads (conflict-free ds_read_b128).
__global__ __launch_bounds__(256, 2) void gemm_pre(
    const u16* __restrict__ X, const u16* __restrict__ Wih,
    const float* __restrict__ bih, const float* __restrict__ bhh,
    u16* __restrict__ Pout)
{
  __shared__ u16 As[128 * 64];
  __shared__ u16 Bs[128 * 64];
  const int tid = threadIdx.x;
  const int lane = tid & 63;
  const int wid = tid >> 6;
  const int wm = wid & 1, wn = wid >> 1;
  const int Mt = blockIdx.x, Nt = blockIdx.y;

  f32x4 acc[4][4] = {};

  const int rsub = lane >> 3;                 // 0..7 (row within 8-row chunk)
  const int src_chunk = (lane & 7) ^ rsub;    // pre-swizzled 16B-chunk of the source

  for (int it = 0; it < 16; ++it) {
    const int k0 = it * 64;
    #pragma unroll
    for (int q = 0; q < 4; ++q) {
      const int j = wid * 4 + q;              // 0..15, 8 rows per instr
      const int row_local = j * 8 + rsub;     // 0..127
      const u16* ga = X   + ((size_t)(Mt * 128 + row_local)) * 1024 + k0 + src_chunk * 8;
      const u16* gb = Wih + ((size_t)(Nt * 128 + row_local)) * 1024 + k0 + src_chunk * 8;
      gload_lds16(ga, (char*)As + j * 1024);
      gload_lds16(gb, (char*)Bs + j * 1024);
    }
    __syncthreads();
    #pragma unroll
    for (int ks = 0; ks < 2; ++ks) {
      short8 af[4], bfv[4];
      #pragma unroll
      for (int f = 0; f < 4; ++f) {
        const int ra = wm * 64 + f * 16 + (lane & 15);
        const int rb = wn * 64 + f * 16 + (lane & 15);
        const int kc = ks * 4 + (lane >> 4);  // 16B chunk index within 128B row
        af[f]  = *(const short8*)((const char*)As + ra * 128 + ((kc ^ (ra & 7)) << 4));
        bfv[f] = *(const short8*)((const char*)Bs + rb * 128 + ((kc ^ (rb & 7)) << 4));
      }
      #pragma unroll
      for (int fm = 0; fm < 4; ++fm)
        #pragma unroll
        for (int fn = 0; fn < 4; ++fn)
          acc[fm][fn] = __builtin_amdgcn_mfma_f32_16x16x32_bf16(af[fm], bfv[fn], acc[fm][fn], 0, 0, 0);
    }
    __syncthreads();
  }

  // epilogue: wave's 64-row band == exactly one t (128-row tile = 2 t values)
  const int t_out = Mt * 2 + wm;
  #pragma unroll
  for (int fn = 0; fn < 4; ++fn) {
    const int n = Nt * 128 + wn * 64 + fn * 16 + (lane & 15);
    const float bias = bih[n] + bhh[n];
    #pragma unroll
    for (int fm = 0; fm < 4; ++fm) {
      const int b = fm * 16 + ((lane >> 4) << 2);
      u16x4 o;
      #pragma unroll
      for (int r = 0; r < 4; ++r) o[r] = f2bf(acc[fm][fn][r] + bias);
      *(u16x4*)(Pout + ((size_t)t_out * 4096 + n) * 64 + b) = o;
    }
  }
}

// ---------------- Phase 2: persistent recurrence ----------------
// 64 WGs x 256 threads. WG w owns hidden units [16w, 16w+16) (=> 64 gate rows).
// LDS: W_hh slice 64x1024 bf16 (128KB, swizzled) + gate exchange 16KB.
__global__ __launch_bounds__(256, 1) void lstm_rec(
    const u16* __restrict__ P, const float* __restrict__ c0,
    const float* __restrict__ Whh, u16* __restrict__ hbuf,
    float* __restrict__ out, int* __restrict__ flags)
{
  __shared__ u16 Ws[64 * 1024];   // slice row s = g*16+u -> W_hh[g*1024 + 16w + u][:]
  __shared__ float GX[4096];      // [g][u][b] f32, swizzled

  const int tid = threadIdx.x;
  const int lane = tid & 63;
  const int wid = tid >> 6;
  const int wg = blockIdx.x;  // 0..63

  // ---- one-time: stage W_hh slice into LDS (bf16, XOR-swizzled rows) ----
  {
    const int rowp = tid >> 2;   // slice row 0..63
    const int q = tid & 3;       // k-quarter
    const int grow = (rowp >> 4) * 1024 + wg * 16 + (rowp & 15);
    const float4* src = (const float4*)(Whh + (size_t)grow * 1024 + q * 256);
    #pragma unroll 2
    for (int j = 0; j < 32; ++j) {
      float4 v0 = src[j * 2];
      float4 v1 = src[j * 2 + 1];
      short8 pk;
      pk[0] = (short)f2bf(v0.x); pk[1] = (short)f2bf(v0.y);
      pk[2] = (short)f2bf(v0.z); pk[3] = (short)f2bf(v0.w);
      pk[4] = (short)f2bf(v1.x); pk[5] = (short)f2bf(v1.y);
      pk[6] = (short)f2bf(v1.z); pk[7] = (short)f2bf(v1.w);
      const int kc = q * 32 + j;  // 8-elem chunk index 0..127
      *(short8*)((char*)Ws + rowp * 2048 + ((kc ^ (rowp & 7)) << 4)) = pk;
    }
  }

  // pointwise role of this thread: unit u, batches b0..b0+3
  const int u = tid & 15;
  const int b0 = (tid >> 4) << 2;
  const int jh = wg * 16 + u;
  float cs[4];
  #pragma unroll
  for (int r = 0; r < 4; ++r) cs[r] = c0[(size_t)(b0 + r) * 1024 + jh];

  const int wm = wid & 1;   // batch half (rows 32*wm..+32)
  const int wn = wid >> 1;  // gate pair (slice cols 32*wn..+32)

  __syncthreads();

  for (int si = 0; si < 256; ++si) {
    const int t = 255 - si;
    const u16* hc = hbuf + (size_t)(si & 1) * (64 * 1024);
    u16*       hn = hbuf + (size_t)((si & 1) ^ 1) * (64 * 1024);

    f32x4 acc[2][2] = {};
    #pragma unroll
    for (int half = 0; half < 2; ++half) {
      // preload this half's A fragments (h rows, LLC-resident) in bulk
      short8 afr[16][2];
      #pragma unroll
      for (int ks = 0; ks < 16; ++ks)
        #pragma unroll
        for (int mi = 0; mi < 2; ++mi) {
          const int row = wm * 32 + mi * 16 + (lane & 15);
          afr[ks][mi] = *(const short8*)(hc + (size_t)row * 1024 + half * 512 + ks * 32 + ((lane >> 4) << 3));
        }
      #pragma unroll
      for (int ks = 0; ks < 16; ++ks) {
        const int kabs = half * 16 + ks;
        #pragma unroll
        for (int ni = 0; ni < 2; ++ni) {
          const int rs = wn * 32 + ni * 16 + (lane & 15);
          const int kcl = kabs * 4 + (lane >> 4);
          const short8 bfr = *(const short8*)((const char*)Ws + rs * 2048 + ((kcl ^ (rs & 7)) << 4));
          acc[0][ni] = __builtin_amdgcn_mfma_f32_16x16x32_bf16(afr[ks][0], bfr, acc[0][ni], 0, 0, 0);
          acc[1][ni] = __builtin_amdgcn_mfma_f32_16x16x32_bf16(afr[ks][1], bfr, acc[1][ni], 0, 0, 0);
        }
      }
    }

    // exchange gates through LDS (swizzled f32x4 writes: rows b..b+3, one (g,u))
    #pragma unroll
    for (int mi = 0; mi < 2; ++mi)
      #pragma unroll
      for (int ni = 0; ni < 2; ++ni) {
        const int g = wn * 2 + ni;
        const int uu = lane & 15;
        const int bb = wm * 32 + mi * 16 + ((lane >> 4) << 2);
        *(f32x4*)((char*)GX + ((((g * 16 + uu) * 64 + bb) << 2) ^ ((uu & 7) << 4))) = acc[mi][ni];
      }
    __syncthreads();

    const f32x4 vi = *(const f32x4*)((char*)GX + ((((0 * 16 + u) * 64 + b0) << 2) ^ ((u & 7) << 4)));
    const f32x4 vf = *(const f32x4*)((char*)GX + ((((1 * 16 + u) * 64 + b0) << 2) ^ ((u & 7) << 4)));
    const f32x4 vg = *(const f32x4*)((char*)GX + ((((2 * 16 + u) * 64 + b0) << 2) ^ ((u & 7) << 4)));
    const f32x4 vo = *(const f32x4*)((char*)GX + ((((3 * 16 + u) * 64 + b0) << 2) ^ ((u & 7) << 4)));

    const size_t pbase = (size_t)t * 4096 * 64;
    const u16x4 pi = *(const u16x4*)(P + pbase + (size_t)(0 * 1024 + jh) * 64 + b0);
    const u16x4 pf = *(const u16x4*)(P + pbase + (size_t)(1 * 1024 + jh) * 64 + b0);
    const u16x4 pg = *(const u16x4*)(P + pbase + (size_t)(2 * 1024 + jh) * 64 + b0);
    const u16x4 po = *(const u16x4*)(P + pbase + (size_t)(3 * 1024 + jh) * 64 + b0);

    #pragma unroll
    for (int r = 0; r < 4; ++r) {
      const float xi = vi[r] + bf2f(pi[r]);
      const float xf = vf[r] + bf2f(pf[r]);
      const float xg = vg[r] + bf2f(pg[r]);
      const float xo = vo[r] + bf2f(po[r]);
      const float ig = 1.f / (1.f + __expf(-xi));
      const float fg = 1.f / (1.f + __expf(-xf));
      const float og = 1.f / (1.f + __expf(-xo));
      const float cn = fg * cs[r] + ig * tanhf(xg);
      const float hv = og * tanhf(cn);
      cs[r] = cn;
      out[((size_t)t * 64 + b0 + r) * 1024 + jh] = hv;
      hn[(size_t)(b0 + r) * 1024 + jh] = f2bf(hv);
      if (si == 255) {
        out[YS_ELEMS + (size_t)(b0 + r) * 1024 + jh] = hv;          // hT
        out[YS_ELEMS + 65536 + (size_t)(b0 + r) * 1024 + jh] = cn;  // cT
      }
    }

    if (si < 255) {
      __threadfence();      // release: write back h/ys (L2 -> LLC)
      __syncthreads();
      if (tid == 0)
        __hip_atomic_store(&flags[wg], si + 1, __ATOMIC_RELEASE, __HIP_MEMORY_SCOPE_AGENT);
      if (tid < 64) {
        while (__hip_atomic_load(&flags[tid], __ATOMIC_RELAXED, __HIP_MEMORY_SCOPE_AGENT) < si + 1)
          __builtin_amdgcn_s_sleep(8);
      }
      __syncthreads();
      __threadfence();      // acquire: invalidate L1/L2 so next h reads are fresh
    }
  }
}

// ---------------- launch ----------------
extern "C" void kernel_launch(void* const* d_in, const int* in_sizes, int n_in,
                              void* d_out, int out_size, void* d_ws, size_t ws_size,
                              hipStream_t stream) {
  const float* x   = (const float*)d_in[0];
  const float* h0  = (const float*)d_in[1];
  const float* c0  = (const float*)d_in[2];
  const float* Wih = (const float*)d_in[3];
  const float* Whh = (const float*)d_in[4];
  const float* bih = (const float*)d_in[5];
  const float* bhh = (const float*)d_in[6];
  float* out = (float*)d_out;

  char* ws = (char*)d_ws;
  u16* x_bf   = (u16*)(ws + 0);           // 33,554,432 B
  u16* wih_bf = (u16*)(ws + 33554432);    //  8,388,608 B
  u16* Pp     = (u16*)(ws + 41943040);    // 134,217,728 B
  u16* hbuf   = (u16*)(ws + 176160768);   //    262,144 B (2 buffers)
  int* flags  = (int*)(ws + 176422912);   //        256 B

  hipMemsetAsync(flags, 0, 256, stream);
  hipLaunchKernelGGL(cast_f32_bf16, dim3(2048), dim3(256), 0, stream, x,   x_bf,   4194304);
  hipLaunchKernelGGL(cast_f32_bf16, dim3(1024), dim3(256), 0, stream, Wih, wih_bf, 1048576);
  hipLaunchKernelGGL(cast_f32_bf16, dim3(64),   dim3(256), 0, stream, h0,  hbuf,   16384);
  hipLaunchKernelGGL(gemm_pre, dim3(128, 32), dim3(256), 0, stream, x_bf, wih_bf, bih, bhh, Pp);

  const u16* Pc = Pp;
  void* kargs[6];
  kargs[0] = (void*)&Pc;
  kargs[1] = (void*)&c0;
  kargs[2] = (void*)&Whh;
  kargs[3] = (void*)&hbuf;
  kargs[4] = (void*)&out;
  kargs[5] = (void*)&flags;
  hipLaunchCooperativeKernel((void*)lstm_rec, dim3(64), dim3(256), kargs, 0, stream);
}

// Round 4
// 3401.129 us; speedup vs baseline: 1.7648x; 1.7648x over previous
//
#include <hip/hip_runtime.h>
#include <stdint.h>
#include <stddef.h>

// Reverse LSTM: T=256, B=64, D=H=1024.
// Phase 0: cast x, W_ih, h0 to bf16 (ws).
// Phase 1: P[t][n][b] = bf16( x[t,b,:]@W_ih[n,:] + b_ih[n] + b_hh[n] )  (bf16 MFMA GEMM)
// Phase 2: persistent cooperative kernel, 64 WGs; per-step gates = P + h@W_hh_sliceT.
//   Fence-free cross-XCD h handoff:
//     writer: h via global_store_short sc0 sc1 (write-through to MALL) -> vmcnt(0)
//             -> flag via atomicAdd (HW-verified cross-XCD RMW class).
//     reader: flag spin via relaxed agent atomic load (R1-proven to observe remote
//             updates) -> h via global_load_dwordx4 sc0 sc1 (bypass stale L1/L2).
//   NO threadfence / buffer_wbl2 / buffer_inv in the step loop.
//   Static LDS kept at EXACTLY 147456 B (the R1-proven launchable size).

typedef unsigned short u16;
typedef __attribute__((ext_vector_type(4))) unsigned short u16x4;
typedef __attribute__((ext_vector_type(8))) short short8;
typedef __attribute__((ext_vector_type(4))) float f32x4;

#define T_LEN 256
#define YS_ELEMS (256 * 64 * 1024)  // 16777216

__device__ __forceinline__ u16 f2bf(float f) {
  union { float f; unsigned int i; } v; v.f = f;
  unsigned int r = v.i + 0x7FFFu + ((v.i >> 16) & 1u);  // RNE
  return (u16)(r >> 16);
}
__device__ __forceinline__ float bf2f(u16 u) {
  union { unsigned int i; float f; } v; v.i = ((unsigned int)u) << 16; return v.f;
}
__device__ __forceinline__ void gload_lds16(const void* g, void* l) {
  __builtin_amdgcn_global_load_lds(
      (const __attribute__((address_space(1))) unsigned int*)g,
      (__attribute__((address_space(3))) unsigned int*)l, 16, 0, 0);
}
__device__ __forceinline__ float sigm_fast(float x) { return 1.f / (1.f + __expf(-x)); }

// issue one 16B device-coherent load (no wait — caller uses counted vmcnt)
#define ISSUE_LD16(dst, ptr)                                            \
  asm volatile("global_load_dwordx4 %0, %1, off sc0 sc1"                \
               : "=v"(dst) : "v"(ptr) : "memory")

// device-coherent 2B write-through store (to MALL)
#define ST16_WT(ptr, val)                                               \
  asm volatile("global_store_short %0, %1, off sc0 sc1"                 \
               :: "v"(ptr), "v"(val) : "memory")

#define WAIT_VM16() do { asm volatile("s_waitcnt vmcnt(16)" ::: "memory"); \
                         __builtin_amdgcn_sched_barrier(0); } while (0)
#define WAIT_VM0()  do { asm volatile("s_waitcnt vmcnt(0)"  ::: "memory"); \
                         __builtin_amdgcn_sched_barrier(0); } while (0)

// ---------------- Phase 0: f32 -> bf16 cast ----------------
__global__ void cast_f32_bf16(const float* __restrict__ src, u16* __restrict__ dst, int n4) {
  int i = blockIdx.x * blockDim.x + threadIdx.x;
  const int stride = gridDim.x * blockDim.x;
  for (; i < n4; i += stride) {
    float4 v = ((const float4*)src)[i];
    u16x4 o;
    o[0] = f2bf(v.x); o[1] = f2bf(v.y); o[2] = f2bf(v.z); o[3] = f2bf(v.w);
    ((u16x4*)dst)[i] = o;
  }
}

// ---------------- Phase 1: pregate GEMM ----------------
// C[M=16384][N=4096] = X[M][1024] * Wih[N][1024]^T + bias, stored as P[t][n][b] bf16.
__global__ __launch_bounds__(256, 2) void gemm_pre(
    const u16* __restrict__ X, const u16* __restrict__ Wih,
    const float* __restrict__ bih, const float* __restrict__ bhh,
    u16* __restrict__ Pout)
{
  __shared__ u16 As[128 * 64];
  __shared__ u16 Bs[128 * 64];
  const int tid = threadIdx.x;
  const int lane = tid & 63;
  const int wid = tid >> 6;
  const int wm = wid & 1, wn = wid >> 1;
  const int Mt = blockIdx.x, Nt = blockIdx.y;

  f32x4 acc[4][4] = {};

  const int rsub = lane >> 3;                 // 0..7 (row within 8-row chunk)
  const int src_chunk = (lane & 7) ^ rsub;    // pre-swizzled 16B-chunk of the source

  for (int it = 0; it < 16; ++it) {
    const int k0 = it * 64;
    #pragma unroll
    for (int q = 0; q < 4; ++q) {
      const int j = wid * 4 + q;              // 0..15, 8 rows per instr
      const int row_local = j * 8 + rsub;     // 0..127
      const u16* ga = X   + ((size_t)(Mt * 128 + row_local)) * 1024 + k0 + src_chunk * 8;
      const u16* gb = Wih + ((size_t)(Nt * 128 + row_local)) * 1024 + k0 + src_chunk * 8;
      gload_lds16(ga, (char*)As + j * 1024);
      gload_lds16(gb, (char*)Bs + j * 1024);
    }
    __syncthreads();
    #pragma unroll
    for (int ks = 0; ks < 2; ++ks) {
      short8 af[4], bfv[4];
      #pragma unroll
      for (int f = 0; f < 4; ++f) {
        const int ra = wm * 64 + f * 16 + (lane & 15);
        const int rb = wn * 64 + f * 16 + (lane & 15);
        const int kc = ks * 4 + (lane >> 4);  // 16B chunk index within 128B row
        af[f]  = *(const short8*)((const char*)As + ra * 128 + ((kc ^ (ra & 7)) << 4));
        bfv[f] = *(const short8*)((const char*)Bs + rb * 128 + ((kc ^ (rb & 7)) << 4));
      }
      #pragma unroll
      for (int fm = 0; fm < 4; ++fm)
        #pragma unroll
        for (int fn = 0; fn < 4; ++fn)
          acc[fm][fn] = __builtin_amdgcn_mfma_f32_16x16x32_bf16(af[fm], bfv[fn], acc[fm][fn], 0, 0, 0);
    }
    __syncthreads();
  }

  // epilogue: wave's 64-row band == exactly one t (128-row tile = 2 t values)
  const int t_out = Mt * 2 + wm;
  #pragma unroll
  for (int fn = 0; fn < 4; ++fn) {
    const int n = Nt * 128 + wn * 64 + fn * 16 + (lane & 15);
    const float bias = bih[n] + bhh[n];
    #pragma unroll
    for (int fm = 0; fm < 4; ++fm) {
      const int b = fm * 16 + ((lane >> 4) << 2);
      u16x4 o;
      #pragma unroll
      for (int r = 0; r < 4; ++r) o[r] = f2bf(acc[fm][fn][r] + bias);
      *(u16x4*)(Pout + ((size_t)t_out * 4096 + n) * 64 + b) = o;
    }
  }
}

// ---------------- Phase 2: persistent recurrence ----------------
// 64 WGs x 256 threads. WG w owns hidden units [16w, 16w+16) (=> 64 gate rows).
// Static LDS = 131072 + 16384 = 147456 B exactly (launchable per R1).
__global__ __launch_bounds__(256, 1) void lstm_rec(
    const u16* __restrict__ P, const float* __restrict__ c0,
    const float* __restrict__ Whh, u16* __restrict__ hbuf,
    float* __restrict__ out, int* __restrict__ flags)
{
  __shared__ u16 Ws[64 * 1024];   // slice row s = g*16+u -> W_hh[g*1024 + 16w + u][:]
  __shared__ float GX[4096];      // [g][u][b] f32, swizzled

  const int tid = threadIdx.x;
  const int lane = tid & 63;
  const int wid = tid >> 6;
  const int wg = blockIdx.x;  // 0..63

  // ---- one-time: stage W_hh slice into LDS (bf16, XOR-swizzled rows) ----
  {
    const int rowp = tid >> 2;   // slice row 0..63
    const int q = tid & 3;       // k-quarter
    const int grow = (rowp >> 4) * 1024 + wg * 16 + (rowp & 15);
    const float4* src = (const float4*)(Whh + (size_t)grow * 1024 + q * 256);
    #pragma unroll 2
    for (int j = 0; j < 32; ++j) {
      float4 v0 = src[j * 2];
      float4 v1 = src[j * 2 + 1];
      short8 pk;
      pk[0] = (short)f2bf(v0.x); pk[1] = (short)f2bf(v0.y);
      pk[2] = (short)f2bf(v0.z); pk[3] = (short)f2bf(v0.w);
      pk[4] = (short)f2bf(v1.x); pk[5] = (short)f2bf(v1.y);
      pk[6] = (short)f2bf(v1.z); pk[7] = (short)f2bf(v1.w);
      const int kc = q * 32 + j;  // 8-elem chunk index 0..127
      *(short8*)((char*)Ws + rowp * 2048 + ((kc ^ (rowp & 7)) << 4)) = pk;
    }
  }

  // pointwise role: unit u, batches b0..b0+3
  const int u = tid & 15;
  const int b0 = (tid >> 4) << 2;
  const int jh = wg * 16 + u;
  float cs[4];
  #pragma unroll
  for (int r = 0; r < 4; ++r) cs[r] = c0[(size_t)(b0 + r) * 1024 + jh];

  const int wm = wid & 1;   // batch half (rows 32*wm..+32)
  const int wn = wid >> 1;  // gate pair (slice cols 32*wn..+32)

  __syncthreads();

  // per-quarter issue / compute macros (K split in 4 quarters of 256)
  #define ISSUE_Q(buf, qi)                                                     \
    _Pragma("unroll")                                                          \
    for (int kq = 0; kq < 8; ++kq) {                                           \
      _Pragma("unroll")                                                        \
      for (int mi = 0; mi < 2; ++mi) {                                         \
        const u16* ap = hc + (size_t)(wm * 32 + mi * 16 + (lane & 15)) * 1024  \
                        + (qi) * 256 + kq * 32 + ((lane >> 4) << 3);           \
        ISSUE_LD16(buf[kq][mi], ap);                                           \
      }                                                                        \
    }

  #define MFMA_Q(buf, qi)                                                      \
    _Pragma("unroll")                                                          \
    for (int kq = 0; kq < 8; ++kq) {                                           \
      const int kabs = (qi) * 8 + kq;                                          \
      _Pragma("unroll")                                                        \
      for (int ni = 0; ni < 2; ++ni) {                                         \
        const int rs = wn * 32 + ni * 16 + (lane & 15);                        \
        const int kcl = kabs * 4 + (lane >> 4);                                \
        const short8 bfr = *(const short8*)((const char*)Ws + rs * 2048        \
                           + ((kcl ^ (rs & 7)) << 4));                         \
        acc[0][ni] = __builtin_amdgcn_mfma_f32_16x16x32_bf16(buf[kq][0], bfr, acc[0][ni], 0, 0, 0); \
        acc[1][ni] = __builtin_amdgcn_mfma_f32_16x16x32_bf16(buf[kq][1], bfr, acc[1][ni], 0, 0, 0); \
      }                                                                        \
    }

  for (int si = 0; si < 256; ++si) {
    const int t = 255 - si;
    const u16* hc = hbuf + (size_t)(si & 1) * (64 * 1024);
    u16*       hn = hbuf + (size_t)((si & 1) ^ 1) * (64 * 1024);

    // P loads for this step (plain cached; complete by the pointwise section)
    const size_t pbase = (size_t)t * 4096 * 64;
    const u16x4 pi = *(const u16x4*)(P + pbase + (size_t)(0 * 1024 + jh) * 64 + b0);
    const u16x4 pf = *(const u16x4*)(P + pbase + (size_t)(1 * 1024 + jh) * 64 + b0);
    const u16x4 pg = *(const u16x4*)(P + pbase + (size_t)(2 * 1024 + jh) * 64 + b0);
    const u16x4 po = *(const u16x4*)(P + pbase + (size_t)(3 * 1024 + jh) * 64 + b0);

    f32x4 acc[2][2] = {};
    short8 afrA[8][2], afrB[8][2];

    // 4-quarter pipelined device-coherent h loads + MFMA
    ISSUE_Q(afrA, 0)
    ISSUE_Q(afrB, 1)
    WAIT_VM16();          // P + q0 ready (q1 partially outstanding)
    MFMA_Q(afrA, 0)
    ISSUE_Q(afrA, 2)
    WAIT_VM16();          // q1 ready
    MFMA_Q(afrB, 1)
    ISSUE_Q(afrB, 3)
    WAIT_VM16();          // q2 ready
    MFMA_Q(afrA, 2)
    WAIT_VM0();           // q3 ready
    MFMA_Q(afrB, 3)

    // exchange gates through LDS (swizzled f32x4 writes)
    #pragma unroll
    for (int mi = 0; mi < 2; ++mi)
      #pragma unroll
      for (int ni = 0; ni < 2; ++ni) {
        const int g = wn * 2 + ni;
        const int uu = lane & 15;
        const int bb = wm * 32 + mi * 16 + ((lane >> 4) << 2);
        *(f32x4*)((char*)GX + ((((g * 16 + uu) * 64 + bb) << 2) ^ ((uu & 7) << 4))) = acc[mi][ni];
      }
    __syncthreads();

    const f32x4 vi = *(const f32x4*)((char*)GX + ((((0 * 16 + u) * 64 + b0) << 2) ^ ((u & 7) << 4)));
    const f32x4 vf = *(const f32x4*)((char*)GX + ((((1 * 16 + u) * 64 + b0) << 2) ^ ((u & 7) << 4)));
    const f32x4 vg = *(const f32x4*)((char*)GX + ((((2 * 16 + u) * 64 + b0) << 2) ^ ((u & 7) << 4)));
    const f32x4 vo = *(const f32x4*)((char*)GX + ((((3 * 16 + u) * 64 + b0) << 2) ^ ((u & 7) << 4)));

    #pragma unroll
    for (int r = 0; r < 4; ++r) {
      const float xi = vi[r] + bf2f(pi[r]);
      const float xf = vf[r] + bf2f(pf[r]);
      const float xg = vg[r] + bf2f(pg[r]);
      const float xo = vo[r] + bf2f(po[r]);
      const float ig = sigm_fast(xi);
      const float fg = sigm_fast(xf);
      const float og = sigm_fast(xo);
      const float cn = fg * cs[r] + ig * tanhf(xg);
      const float hv = og * tanhf(cn);
      cs[r] = cn;
      out[((size_t)t * 64 + b0 + r) * 1024 + jh] = hv;   // ys (plain cached store)
      if (si < 255) {
        // h push: 2B write-through store straight to MALL (no dirty L2 line)
        const unsigned int hb = (unsigned int)f2bf(hv);
        ST16_WT(hn + (size_t)(b0 + r) * 1024 + jh, hb);
      } else {
        out[YS_ELEMS + (size_t)(b0 + r) * 1024 + jh] = hv;          // hT
        out[YS_ELEMS + 65536 + (size_t)(b0 + r) * 1024 + jh] = cn;  // cT
      }
    }

    if (si < 255) {
      asm volatile("s_waitcnt vmcnt(0)" ::: "memory");  // h stores performed at MALL
      __syncthreads();                                   // whole WG drained
      if (tid == 0) atomicAdd(&flags[wg], 1);            // device-scope RMW flag
      if (tid < 64) {
        while (__hip_atomic_load(&flags[tid], __ATOMIC_RELAXED, __HIP_MEMORY_SCOPE_AGENT) < si + 1)
          __builtin_amdgcn_s_sleep(2);
      }
      __syncthreads();
    }
  }
  #undef ISSUE_Q
  #undef MFMA_Q
}

// ---------------- launch ----------------
extern "C" void kernel_launch(void* const* d_in, const int* in_sizes, int n_in,
                              void* d_out, int out_size, void* d_ws, size_t ws_size,
                              hipStream_t stream) {
  const float* x   = (const float*)d_in[0];
  const float* h0  = (const float*)d_in[1];
  const float* c0  = (const float*)d_in[2];
  const float* Wih = (const float*)d_in[3];
  const float* Whh = (const float*)d_in[4];
  const float* bih = (const float*)d_in[5];
  const float* bhh = (const float*)d_in[6];
  float* out = (float*)d_out;

  char* ws = (char*)d_ws;
  u16* x_bf   = (u16*)(ws + 0);           // 33,554,432 B
  u16* wih_bf = (u16*)(ws + 33554432);    //  8,388,608 B
  u16* Pp     = (u16*)(ws + 41943040);    // 134,217,728 B
  u16* hbuf   = (u16*)(ws + 176160768);   //    262,144 B (2 buffers)
  int* flags  = (int*)(ws + 176422912);   //        256 B

  hipMemsetAsync(flags, 0, 256, stream);
  hipLaunchKernelGGL(cast_f32_bf16, dim3(2048), dim3(256), 0, stream, x,   x_bf,   4194304);
  hipLaunchKernelGGL(cast_f32_bf16, dim3(1024), dim3(256), 0, stream, Wih, wih_bf, 1048576);
  hipLaunchKernelGGL(cast_f32_bf16, dim3(64),   dim3(256), 0, stream, h0,  hbuf,   16384);
  hipLaunchKernelGGL(gemm_pre, dim3(128, 32), dim3(256), 0, stream, x_bf, wih_bf, bih, bhh, Pp);

  const u16* Pc = Pp;
  void* kargs[6];
  kargs[0] = (void*)&Pc;
  kargs[1] = (void*)&c0;
  kargs[2] = (void*)&Whh;
  kargs[3] = (void*)&hbuf;
  kargs[4] = (void*)&out;
  kargs[5] = (void*)&flags;
  hipLaunchCooperativeKernel((void*)lstm_rec, dim3(64), dim3(256), kargs, 0, stream);
}